// Round 2
// baseline (15094.315 us; speedup 1.0000x reference)
//
#include <hip/hip_runtime.h>
#include <math.h>

#define B_ 2
#define T_ 2048
#define D_ 2048
#define N_ 8
#define H_ 256
#define F_ 16384
#define BT_ (B_*T_)
#define BIG_NEG -2.3819763e38f

// ---------------- RMSNorm: one block per row (D=2048, 256 threads x 8 elems) ----------------
__global__ __launch_bounds__(256) void rmsnorm_kernel(
    const float* __restrict__ x, const float* __restrict__ scale,
    float* __restrict__ out) {
  int row = blockIdx.x;
  const float* xr = x + (long)row * D_;
  float* orow = out + (long)row * D_;
  int t = threadIdx.x;
  float4 v0 = *(const float4*)(xr + t*4);
  float4 v1 = *(const float4*)(xr + 1024 + t*4);
  float ss = v0.x*v0.x + v0.y*v0.y + v0.z*v0.z + v0.w*v0.w
           + v1.x*v1.x + v1.y*v1.y + v1.z*v1.z + v1.w*v1.w;
#pragma unroll
  for (int off = 1; off < 64; off <<= 1) ss += __shfl_xor(ss, off);
  __shared__ float red[4];
  int wave = t >> 6, lane = t & 63;
  if (lane == 0) red[wave] = ss;
  __syncthreads();
  float tot = red[0] + red[1] + red[2] + red[3];
  float rs = rsqrtf(tot * (1.0f / D_) + 1e-6f);
  float4 s0 = *(const float4*)(scale + t*4);
  float4 s1 = *(const float4*)(scale + 1024 + t*4);
  float4 o0, o1;
  o0.x = v0.x * rs * (1.0f + s0.x);
  o0.y = v0.y * rs * (1.0f + s0.y);
  o0.z = v0.z * rs * (1.0f + s0.z);
  o0.w = v0.w * rs * (1.0f + s0.w);
  o1.x = v1.x * rs * (1.0f + s1.x);
  o1.y = v1.y * rs * (1.0f + s1.y);
  o1.z = v1.z * rs * (1.0f + s1.z);
  o1.w = v1.w * rs * (1.0f + s1.w);
  *(float4*)(orow + t*4) = o0;
  *(float4*)(orow + 1024 + t*4) = o1;
}

// ---------------- generic fp32 GEMM: C[M x Nc] = A[M x Kd] * B(d,j) ----------------
// B(d,j) = Bw[(j/groupG)*groupStride + d*ldb + (j%groupG)]  (handles (N,D,H) weights)
// Tiles: 128x128, BK=16, 256 threads, 8x8 micro-tile. All dims assumed divisible.
enum { EPI_STORE = 0, EPI_ADD = 1, EPI_ACCUM = 2, EPI_GELUMUL = 3 };

__device__ inline float gelu_f(float x) {
  float x3 = x * x * x;
  return 0.5f * x * (1.0f + tanhf(0.7978845608028654f * (x + 0.044715f * x3)));
}

template <int EPI>
__global__ __launch_bounds__(256) void gemm_f32(
    const float* __restrict__ A, int lda,
    const float* __restrict__ Bw, int ldb,
    int Kd, int groupG, long groupStride,
    const float* __restrict__ R, int ldr,
    float* __restrict__ C, int ldc) {
  __shared__ float As[16][132];
  __shared__ float Bs[16][132];
  int row0 = blockIdx.y * 128;
  int col0 = blockIdx.x * 128;
  const float* Bbase = Bw + (long)(col0 / groupG) * groupStride + (col0 % groupG);
  int tid = threadIdx.x;
  int tx = tid & 15, ty = tid >> 4;
  float acc[8][8];
#pragma unroll
  for (int i = 0; i < 8; i++)
#pragma unroll
    for (int j = 0; j < 8; j++) acc[i][j] = 0.f;

  for (int k0 = 0; k0 < Kd; k0 += 16) {
    {
      int r = tid >> 2, c4 = (tid & 3) * 4;
#pragma unroll
      for (int i = 0; i < 2; i++) {
        float4 a = *(const float4*)(A + (long)(row0 + r + i*64) * lda + k0 + c4);
        As[c4+0][r + i*64] = a.x;
        As[c4+1][r + i*64] = a.y;
        As[c4+2][r + i*64] = a.z;
        As[c4+3][r + i*64] = a.w;
      }
      int rb = tid >> 5, cb = (tid & 31) * 4;
#pragma unroll
      for (int i = 0; i < 2; i++) {
        *(float4*)(&Bs[rb + i*8][cb]) =
            *(const float4*)(Bbase + (long)(k0 + rb + i*8) * ldb + cb);
      }
    }
    __syncthreads();
#pragma unroll
    for (int kk = 0; kk < 16; kk++) {
      float a8[8], b8[8];
      *(float4*)(a8)     = *(const float4*)(&As[kk][ty*8]);
      *(float4*)(a8 + 4) = *(const float4*)(&As[kk][ty*8 + 4]);
      *(float4*)(b8)     = *(const float4*)(&Bs[kk][tx*8]);
      *(float4*)(b8 + 4) = *(const float4*)(&Bs[kk][tx*8 + 4]);
#pragma unroll
      for (int i = 0; i < 8; i++)
#pragma unroll
        for (int j = 0; j < 8; j++)
          acc[i][j] = fmaf(a8[i], b8[j], acc[i][j]);
    }
    __syncthreads();
  }

#pragma unroll
  for (int i = 0; i < 8; i++) {
    long crow = (long)(row0 + ty*8 + i);
    float* cp = C + crow * ldc + col0 + tx*8;
    float vals[8];
    if constexpr (EPI == EPI_STORE) {
#pragma unroll
      for (int j = 0; j < 8; j++) vals[j] = acc[i][j];
    } else if constexpr (EPI == EPI_ADD) {
      const float* rp = R + crow * ldr + col0 + tx*8;
      float4 r0 = *(const float4*)rp, r1 = *(const float4*)(rp + 4);
      vals[0] = acc[i][0] + r0.x; vals[1] = acc[i][1] + r0.y;
      vals[2] = acc[i][2] + r0.z; vals[3] = acc[i][3] + r0.w;
      vals[4] = acc[i][4] + r1.x; vals[5] = acc[i][5] + r1.y;
      vals[6] = acc[i][6] + r1.z; vals[7] = acc[i][7] + r1.w;
    } else if constexpr (EPI == EPI_ACCUM) {
      float4 c0 = *(const float4*)cp, c1 = *(const float4*)(cp + 4);
      vals[0] = acc[i][0] + c0.x; vals[1] = acc[i][1] + c0.y;
      vals[2] = acc[i][2] + c0.z; vals[3] = acc[i][3] + c0.w;
      vals[4] = acc[i][4] + c1.x; vals[5] = acc[i][5] + c1.y;
      vals[6] = acc[i][6] + c1.z; vals[7] = acc[i][7] + c1.w;
    } else {  // EPI_GELUMUL: C = gelu(R) * acc   (R==C in-place is safe: each
              // thread reads exactly the elements it writes, after acc is done)
      const float* rp = R + crow * ldr + col0 + tx*8;
#pragma unroll
      for (int j = 0; j < 8; j++) vals[j] = gelu_f(rp[j]) * acc[i][j];
    }
    *(float4*)cp = *(float4*)(vals);
    *(float4*)(cp + 4) = *(float4*)(vals + 4);
  }
}

// ---------------- RoPE in-place on q (scaled by H^-0.5) and k ----------------
// q layout: (BT, N*H); kv layout: (BT, 512) [k cols 0..255, v cols 256..511]
// Matches reference arithmetic: timescale = 10000^(2j/H) in fp32, rad = pos/ts.
__global__ __launch_bounds__(256) void rope_kernel(
    float* __restrict__ q, float* __restrict__ kv, const int* __restrict__ positions) {
  int idx = blockIdx.x * 256 + threadIdx.x;
  const int QP = BT_ * N_ * 128;  // q rotation pairs
  float* p1;
  int j, pos;
  float sc;
  if (idx < QP) {
    int bt = idx >> 10;       // N_*128 = 1024
    int r = idx & 1023;
    int n = r >> 7;
    j = r & 127;
    pos = positions[bt];
    p1 = q + (long)bt * 2048 + n * 256 + j;
    sc = 0.0625f;             // H^-0.5
  } else {
    int i2 = idx - QP;        // < BT_*128
    int bt = i2 >> 7;
    j = i2 & 127;
    pos = positions[bt];
    p1 = kv + (long)bt * 512 + j;
    sc = 1.0f;
  }
  float* p2 = p1 + 128;
  float ts = powf(10000.0f, (float)j * (2.0f / 256.0f));
  float rad = (float)pos / ts;
  float s, c;
  sincosf(rad, &s, &c);
  float x1 = *p1, x2 = *p2;
  *p1 = (x1 * c - x2 * s) * sc;
  *p2 = (x2 * c + x1 * s) * sc;
}

// ---------------- causal MQA attention, flash-style, 1 wave per 4 queries ----------------
#define TQ 4
__global__ __launch_bounds__(256) void attn_kernel(
    const float* __restrict__ q, const float* __restrict__ kv,
    float* __restrict__ enc) {
  int wave = threadIdx.x >> 6, lane = threadIdx.x & 63;
  int gw = blockIdx.x * 4 + wave;
  const int TPB = T_ / TQ;  // 512
  int b = gw / (N_ * TPB);
  int rem = gw % (N_ * TPB);
  int n = rem / TPB;
  int t0 = (rem % TPB) * TQ;

  const float* qp = q + (long)(b * T_ + t0) * (N_ * H_) + n * H_ + lane * 4;
  float4 qr[TQ];
#pragma unroll
  for (int i = 0; i < TQ; i++) qr[i] = *(const float4*)(qp + (long)i * (N_ * H_));

  const float* kp = kv + (long)(b * T_) * 512 + lane * 4;        // k row stride 512
  const float* vp = kp + 256;

  float m[TQ], l[TQ];
  float4 acc[TQ];
#pragma unroll
  for (int i = 0; i < TQ; i++) {
    m[i] = -3.0e38f; l[i] = 0.f; acc[i] = make_float4(0.f, 0.f, 0.f, 0.f);
  }
  int send = t0 + TQ;
  for (int s = 0; s < send; ++s) {
    float4 k4 = *(const float4*)(kp + (long)s * 512);
    float4 v4 = *(const float4*)(vp + (long)s * 512);
#pragma unroll
    for (int i = 0; i < TQ; i++) {
      float d = qr[i].x * k4.x + qr[i].y * k4.y + qr[i].z * k4.z + qr[i].w * k4.w;
#pragma unroll
      for (int off = 1; off < 64; off <<= 1) d += __shfl_xor(d, off);
      float score = (s <= t0 + i) ? d : BIG_NEG;
      float mn = fmaxf(m[i], score);
      float corr = __expf(m[i] - mn);
      float p = __expf(score - mn);
      l[i] = l[i] * corr + p;
      acc[i].x = acc[i].x * corr + p * v4.x;
      acc[i].y = acc[i].y * corr + p * v4.y;
      acc[i].z = acc[i].z * corr + p * v4.z;
      acc[i].w = acc[i].w * corr + p * v4.w;
      m[i] = mn;
    }
  }
#pragma unroll
  for (int i = 0; i < TQ; i++) {
    float inv = 1.0f / l[i];
    float4 o = make_float4(acc[i].x * inv, acc[i].y * inv, acc[i].z * inv, acc[i].w * inv);
    *(float4*)(enc + (long)(b * T_ + t0 + i) * 2048 + n * 256 + lane * 4) = o;
  }
}

// ---------------- launch ----------------
// Workspace budget (floats): h(BT*2048) + enc/chunk(BT*2048) + kv(BT*512)
//   = 32MB + 32MB + 8MB = 72MB.  q is staged in d_out (dead until w_o GEMM).
extern "C" void kernel_launch(void* const* d_in, const int* in_sizes, int n_in,
                              void* d_out, int out_size, void* d_ws, size_t ws_size,
                              hipStream_t stream) {
  const float* x      = (const float*)d_in[0];
  const int*   pos    = (const int*)d_in[1];
  // d_in[2] attn_mask: deterministic causal tril -> hardcoded in attn kernel
  const float* sc_att = (const float*)d_in[3];
  const float* w_q    = (const float*)d_in[4];
  const float* w_kv   = (const float*)d_in[5];
  const float* w_o    = (const float*)d_in[6];
  const float* sc_ffn = (const float*)d_in[7];
  const float* w_g    = (const float*)d_in[8];
  const float* w_l    = (const float*)d_in[9];
  float* out = (float*)d_out;

  float* ws = (float*)d_ws;
  float* hb  = ws;                          // BT x 2048 (h, later h2)
  float* eb  = hb + (long)BT_ * 2048;       // BT x 2048 (enc, later gate/ff chunk)
  float* kvb = eb + (long)BT_ * 2048;       // BT x 512  (k|v)
  float* qb  = out;                         // q staged in d_out (overwritten by w_o GEMM)

  dim3 blk(256);

  // h = rmsnorm(x, scale_attn)
  rmsnorm_kernel<<<BT_, blk, 0, stream>>>(x, sc_att, hb);
  // q = h @ w_q   (w_q (N,D,H): groupG=H, groupStride=D*H)
  gemm_f32<EPI_STORE><<<dim3(16, 32), blk, 0, stream>>>(
      hb, 2048, w_q, 256, 2048, 256, (long)2048 * 256, nullptr, 0, qb, 2048);
  // k|v = h @ w_kv (cols 0-255 -> c=0, 256-511 -> c=1; group stride = K*D*H)
  gemm_f32<EPI_STORE><<<dim3(4, 32), blk, 0, stream>>>(
      hb, 2048, w_kv, 256, 2048, 256, (long)2048 * 256, nullptr, 0, kvb, 512);
  // rope(q)*H^-0.5, rope(k)
  rope_kernel<<<18432, blk, 0, stream>>>(qb, kvb, pos);
  // enc = causal-softmax(q k^T) v
  attn_kernel<<<2048, blk, 0, stream>>>(qb, kvb, eb);
  // out = x + enc @ w_o  (reads A=eb, R=x only; overwrites q in d_out — safe)
  gemm_f32<EPI_ADD><<<dim3(16, 32), blk, 0, stream>>>(
      eb, 2048, w_o, 2048, 2048, 1 << 30, 0, x, 2048, out, 2048);
  // h2 = rmsnorm(out, scale_ffn)
  rmsnorm_kernel<<<BT_, blk, 0, stream>>>(out, sc_ffn, hb);
  // FFN in 8 chunks of Fc=2048, chunk buffer = eb (gate, then ff in-place):
  for (int c = 0; c < 8; c++) {
    const float* g0 = w_g + (long)c * 2048;
    const float* g1 = w_g + (long)D_ * F_ + (long)c * 2048;
    const float* wl = w_l + (long)c * 2048 * D_;
    // gate -> eb
    gemm_f32<EPI_STORE><<<dim3(16, 32), blk, 0, stream>>>(
        hb, 2048, g0, F_, 2048, 1 << 30, 0, nullptr, 0, eb, 2048);
    // eb = gelu(eb) * (h2 @ g1)   (in-place R==C, element-exact ownership)
    gemm_f32<EPI_GELUMUL><<<dim3(16, 32), blk, 0, stream>>>(
        hb, 2048, g1, F_, 2048, 1 << 30, 0, eb, 2048, eb, 2048);
    // out += eb @ wl
    gemm_f32<EPI_ACCUM><<<dim3(16, 32), blk, 0, stream>>>(
        eb, 2048, wl, 2048, 2048, 1 << 30, 0, nullptr, 0, out, 2048);
  }
}